// Round 5
// baseline (140.726 us; speedup 1.0000x reference)
//
#include <hip/hip_runtime.h>
#include <math.h>

#define B 1024
#define D 128
#define TDIM 1
#define NB 256
#define NT 256

constexpr float THR   = 0.05f;
constexpr float LAM1f = 1.0f;
constexpr float LAM2f = 0.5f;
constexpr float EPSf  = 1e-8f;
constexpr float QS    = 16777216.0f;     // 2^24 fixed-point scale
constexpr double QI   = 1.0 / 16777216.0;

struct alignas(64) Part { float loss; unsigned cnt; unsigned pad_[14]; };

struct Ptrs {
  const float* x; const float* y;
  unsigned* cnt; unsigned* ticket;
  unsigned* h0; unsigned* h1; unsigned* h2;
  unsigned long long* csum; unsigned long long* csq;
  float* xcol1; float* xn; float* r2o;
  Part* parts; float* out;
};

struct SelOut { unsigned total, bucket, rem; };

// cooperative 256-thread radix-select over a histogram level (pure integer
// math on identical global data -> bit-identical in every block)
__device__ SelOut block_select(const unsigned* __restrict__ h, int nb, unsigned kk_in) {
  int t = threadIdx.x;
  const int per = nb >> 8;                 // 8 (nb=2048) or 4 (nb=1024)
  unsigned local[8];
  unsigned lsum = 0;
#pragma unroll
  for (int q = 0; q < 8; ++q) {
    unsigned v = (q < per) ? h[t * per + q] : 0u;
    local[q] = v; lsum += v;
  }
  unsigned incl = lsum;
#pragma unroll
  for (int o = 1; o < 64; o <<= 1) {
    unsigned nbr = __shfl_up(incl, o, 64);
    if ((t & 63) >= o) incl += nbr;
  }
  __shared__ unsigned sel_wsum[4];
  __shared__ unsigned sel_res[3];
  if ((t & 63) == 63) sel_wsum[t >> 6] = incl;
  __syncthreads();
  unsigned wpre = 0;
  for (int wv = 0; wv < (t >> 6); ++wv) wpre += sel_wsum[wv];
  incl += wpre;
  unsigned excl = incl - lsum;
  if (t == 255) sel_res[0] = incl;
  __syncthreads();
  unsigned total = sel_res[0];
  unsigned kk = (kk_in == 0xFFFFFFFFu) ? ((total ? total - 1u : 0u) >> 1) : kk_in;
  if (total && kk >= excl && kk < incl) {   // exactly one thread
    unsigned cum = excl;
    for (int q = 0; q < per; ++q) {
      if (cum + local[q] > kk) { sel_res[1] = (unsigned)(t * per + q); sel_res[2] = kk - cum; break; }
      cum += local[q];
    }
  }
  __syncthreads();
  SelOut o; o.total = total; o.bucket = sel_res[1]; o.rem = sel_res[2];
  return o;
}

// grid barrier: monotonic counter, zeroed per call by init_zero.
__device__ __forceinline__ void gsync(unsigned* cnt, int phase) {
  __syncthreads();
  if (threadIdx.x == 0) {
    __threadfence();                                        // release
    __hip_atomic_fetch_add(cnt, 1u, __ATOMIC_RELAXED, __HIP_MEMORY_SCOPE_AGENT);
    unsigned target = (unsigned)(NB * (phase + 1));
    while (__hip_atomic_load(cnt, __ATOMIC_RELAXED, __HIP_MEMORY_SCOPE_AGENT) < target)
      __builtin_amdgcn_s_sleep(1);
    __threadfence();                                        // acquire
  }
  __syncthreads();
}

__global__ void __launch_bounds__(NT) init_zero(unsigned* z, int n) {
  for (int i = threadIdx.x; i < n; i += NT) z[i] = 0u;
}

__global__ void __launch_bounds__(NT) mega(Ptrs p) {
  const int b = blockIdx.x;      // 0..255
  const int t = threadIdx.x;     // 0..255
  const int r0 = b << 2;         // 4 rows per block

  __shared__ float redf[NT];
  __shared__ float red3[3 * NT];
  __shared__ unsigned lh[2048];
  __shared__ float sh_bcast[2];
  __shared__ float xi_sh[D];
  __shared__ unsigned short jlist[B];
  __shared__ unsigned wcnt_sh[4];
  __shared__ int last_sh;

  // ================= P0: quantized column sums + x[:,1] gather =============
  float a0 = 0.f, a1 = 0.f, a2 = 0.f, a3 = 0.f;
  if (t < D) {
    a0 = p.x[(r0 + 0) * D + t];
    a1 = p.x[(r0 + 1) * D + t];
    a2 = p.x[(r0 + 2) * D + t];
    a3 = p.x[(r0 + 3) * D + t];
    long long qs = llrintf(a0 * QS) + llrintf(a1 * QS)
                 + llrintf(a2 * QS) + llrintf(a3 * QS);
    long long qq = llrintf(a0 * a0 * QS) + llrintf(a1 * a1 * QS)
                 + llrintf(a2 * a2 * QS) + llrintf(a3 * a3 * QS);
    atomicAdd(&p.csum[t], (unsigned long long)qs);
    atomicAdd(&p.csq[t],  (unsigned long long)qq);
    if (t == TDIM) {
      p.xcol1[r0 + 0] = a0; p.xcol1[r0 + 1] = a1;
      p.xcol1[r0 + 2] = a2; p.xcol1[r0 + 3] = a3;
    }
  }
  gsync(p.cnt, 0);

  // ===== P1: finalize col stats (redundant, register-resident), normalize,
  // =====     and build histogram level 0 ====================================
  float m_c = 0.f, s_c = 1.f;
  if (t < D) {
    long long sll = (long long)p.csum[t];
    long long qll = (long long)p.csq[t];
    double sum  = (double)sll * QI;
    double ssq  = (double)qll * QI;
    double mean = sum * (1.0 / 1024.0);
    double var  = (ssq - sum * mean) * (1.0 / 1023.0);
    float sd = (float)sqrt(var > 0.0 ? var : 0.0);
    if (sd < 1e-6f) sd = 1e-6f;
    m_c = (float)mean; s_c = sd;
    if (t == TDIM) { sh_bcast[0] = m_c; sh_bcast[1] = 1.0f / sd; }
  }
  __syncthreads();
  const float m1 = sh_bcast[0];
  const float inv_s1 = sh_bcast[1];

  // normalize own 4 rows (x values still in registers), write xn + r2o
  {
    float vv[4] = {a0, a1, a2, a3};
    for (int rr = 0; rr < 4; ++rr) {
      int row = r0 + rr;
      float v = 0.f;
      if (t < D) {
        v = (vv[rr] - m_c) / s_c;
        p.xn[row * D + t] = v;
      }
      redf[t] = (t < D && t != TDIM) ? v * v : 0.f;
      __syncthreads();
      for (int o = 128; o > 0; o >>= 1) { if (t < o) redf[t] += redf[t + o]; __syncthreads(); }
      if (t == 0) p.r2o[row] = redf[0];
      __syncthreads();
    }
  }

  // histogram level 0 over masked d2 keys (top 11 bits)
  for (int q = t; q < 2048; q += NT) lh[q] = 0;
  __syncthreads();
  for (int rr = 0; rr < 4; ++rr) {
    int i = r0 + rr;
    float yi = p.y[i];
    float xi1 = p.xcol1[i];
    for (int j = t; j < B; j += NT) {
      if (j == i) continue;
      if (fabsf(yi - p.y[j]) > THR) continue;
      float dz = (xi1 - p.xcol1[j]) * inv_s1;
      atomicAdd(&lh[__float_as_uint(dz * dz) >> 21], 1u);
    }
  }
  __syncthreads();
  for (int q = t; q < 2048; q += NT) { unsigned c = lh[q]; if (c) atomicAdd(&p.h0[q], c); }
  gsync(p.cnt, 1);

  // ================= P2: histogram level 1 (mid 11 bits) ====================
  SelOut s0 = block_select(p.h0, 2048, 0xFFFFFFFFu);
  if (s0.total) {
    for (int q = t; q < 2048; q += NT) lh[q] = 0;
    __syncthreads();
    for (int rr = 0; rr < 4; ++rr) {
      int i = r0 + rr;
      float yi = p.y[i];
      float xi1 = p.xcol1[i];
      for (int j = t; j < B; j += NT) {
        if (j == i) continue;
        if (fabsf(yi - p.y[j]) > THR) continue;
        float dz = (xi1 - p.xcol1[j]) * inv_s1;
        unsigned bits = __float_as_uint(dz * dz);
        if ((bits >> 21) == s0.bucket) atomicAdd(&lh[(bits >> 10) & 0x7FFu], 1u);
      }
    }
    __syncthreads();
    for (int q = t; q < 2048; q += NT) { unsigned c = lh[q]; if (c) atomicAdd(&p.h1[q], c); }
  }
  gsync(p.cnt, 2);

  // ================= P3: histogram level 2 (low 10 bits) ====================
  SelOut s1s; s1s.bucket = 0; s1s.rem = 0;
  if (s0.total) {
    s1s = block_select(p.h1, 2048, s0.rem);
    unsigned pref = (s0.bucket << 11) | s1s.bucket;
    for (int q = t; q < 1024; q += NT) lh[q] = 0;
    __syncthreads();
    for (int rr = 0; rr < 4; ++rr) {
      int i = r0 + rr;
      float yi = p.y[i];
      float xi1 = p.xcol1[i];
      for (int j = t; j < B; j += NT) {
        if (j == i) continue;
        if (fabsf(yi - p.y[j]) > THR) continue;
        float dz = (xi1 - p.xcol1[j]) * inv_s1;
        unsigned bits = __float_as_uint(dz * dz);
        if ((bits >> 10) == pref) atomicAdd(&lh[bits & 0x3FFu], 1u);
      }
    }
    __syncthreads();
    for (int q = t; q < 1024; q += NT) { unsigned c = lh[q]; if (c) atomicAdd(&p.h2[q], c); }
  }
  gsync(p.cnt, 3);

  // ================= P4: pairwise pass + fused finalize =====================
  float T = 2.0f;
  if (s0.total) {
    SelOut s2s = block_select(p.h2, 1024, s1s.rem);
    unsigned bits = (s0.bucket << 21) | (s1s.bucket << 10) | s2s.bucket;
    T = fmaxf(__uint_as_float(bits), 1e-6f);
  }
  const float invT = 1.0f / T;

  float loss_acc = 0.f; unsigned cnt_acc = 0;   // used at t==0 only

  for (int rr = 0; rr < 4; ++rr) {
    int i = r0 + rr;
    float yi = p.y[i];
    float zi = (p.xcol1[i] - m1) * inv_s1;
    float ri = p.r2o[i];
    if (t < D) xi_sh[t] = p.xn[i * D + t];

    // den1 over ALL j (j==i contributes exp(0)=1; removed after reduce)
    float4 xc = *(const float4*)(p.xcol1 + 4 * t);
    float z0 = (xc.x - m1) * inv_s1, z1v = (xc.y - m1) * inv_s1;
    float z2v = (xc.z - m1) * inv_s1, z3 = (xc.w - m1) * inv_s1;
    float d0 = zi - z0, d1 = zi - z1v, d2v = zi - z2v, d3 = zi - z3;
    float den1 = __expf(-d0 * d0 * invT) + __expf(-d1 * d1 * invT)
               + __expf(-d2v * d2v * invT) + __expf(-d3 * d3 * invT);

    // deterministic ballot-compaction of same-age neighbors
    unsigned base = 0;
    {
      int lane = t & 63, wv = t >> 6;
      for (int rnd = 0; rnd < 4; ++rnd) {
        int j = rnd * 256 + t;
        bool ok = (j != i) && (fabsf(yi - p.y[j]) <= THR);
        unsigned long long mk = __ballot(ok);
        if (lane == 0) wcnt_sh[wv] = (unsigned)__popcll(mk);
        __syncthreads();
        unsigned pre = base;
        for (int w2 = 0; w2 < wv; ++w2) pre += wcnt_sh[w2];
        if (ok) {
          unsigned mypos = (unsigned)__popcll(mk & ((1ull << lane) - 1ull));
          jlist[pre + mypos] = (unsigned short)j;
        }
        base += wcnt_sh[0] + wcnt_sh[1] + wcnt_sh[2] + wcnt_sh[3];
        __syncthreads();
      }
    }
    unsigned cntrow = base;

    float num = 0.f, den2 = 0.f;
    for (unsigned q = t; q < cntrow; q += NT) {
      int j = jlist[q];
      float zj = (p.xcol1[j] - m1) * inv_s1;
      float dz = zi - zj;
      num += __expf(-dz * dz * invT);
      const float* xj = p.xn + j * D;
      float dot = 0.f;
#pragma unroll
      for (int d = 0; d < D; d += 4) {
        float4 a  = *(const float4*)(xi_sh + d);
        float4 bb = *(const float4*)(xj + d);
        dot += a.x * bb.x + a.y * bb.y + a.z * bb.z + a.w * bb.w;
      }
      float dot_o = dot - xi_sh[TDIM] * xj[TDIM];
      float sq = fmaxf((ri + p.r2o[j] - 2.f * dot_o) * (1.0f / 127.0f), 0.f);
      den2 += __expf(-sq * invT);
    }

    red3[t] = num; red3[NT + t] = den1; red3[2 * NT + t] = den2;
    __syncthreads();
    for (int o = 128; o > 0; o >>= 1) {
      if (t < o) {
        red3[t] += red3[t + o];
        red3[NT + t] += red3[NT + t + o];
        red3[2 * NT + t] += red3[2 * NT + t + o];
      }
      __syncthreads();
    }
    if (t == 0 && cntrow > 0) {
      float den1t = red3[NT] - 1.0f;                 // drop j==i term
      float denom = LAM1f * den1t + LAM2f * red3[2 * NT] + EPSf;
      float frac = fminf(fmaxf(red3[0] / denom, 1e-12f), 1.0f - 1e-7f);
      loss_acc += -__logf(frac);
      cnt_acc++;
    }
    __syncthreads();
  }

  // ticket-based deterministic finalize (last block reduces 256 partials)
  if (t == 0) {
    p.parts[b].loss = loss_acc;
    p.parts[b].cnt  = cnt_acc;
    __threadfence();
    unsigned my = atomicAdd(p.ticket, 1u);
    last_sh = (my == NB - 1) ? 1 : 0;
    if (last_sh) __threadfence();
  }
  __syncthreads();
  if (last_sh) {
    red3[t] = p.parts[t].loss;
    redf[t] = (float)p.parts[t].cnt;
    __syncthreads();
    for (int o = 128; o > 0; o >>= 1) {
      if (t < o) { red3[t] += red3[t + o]; redf[t] += redf[t + o]; }
      __syncthreads();
    }
    if (t == 0) p.out[0] = (redf[0] > 0.f) ? red3[0] / redf[0] : 0.f;
  }
}

extern "C" void kernel_launch(void* const* d_in, const int* in_sizes, int n_in,
                              void* d_out, int out_size, void* d_ws, size_t ws_size,
                              hipStream_t stream) {
  const float* x = (const float*)d_in[0];   // (1024,128) f32
  const float* y = (const float*)d_in[1];   // (1024,)    f32
  float* out = (float*)d_out;               // scalar f32

  char* w = (char*)d_ws;
  unsigned* zb = (unsigned*)w;

  Ptrs P;
  P.x = x; P.y = y; P.out = out;
  P.cnt    = zb;                 // [0]
  P.ticket = zb + 1;             // [1]   ([2,3] pad)
  P.h0 = zb + 4;                 // 2048
  P.h1 = zb + 2052;              // 2048
  P.h2 = zb + 4100;              // 1024
  P.csum = (unsigned long long*)(zb + 5124);   // 128 x u64
  P.csq  = (unsigned long long*)(zb + 5380);   // 128 x u64  (zero thru 5636)
  P.parts = (Part*)(w + 22592);                // 64B aligned, 16 KB
  P.xcol1 = (float*)(w + 38976);               // 4 KB, 16B aligned
  P.xn    = (float*)(w + 43072);               // 512 KB, 16B aligned
  P.r2o   = (float*)(w + 567360);              // 4 KB

  init_zero<<<1, NT, 0, stream>>>(zb, 5636);

  void* args[] = { &P };
  hipLaunchCooperativeKernel(reinterpret_cast<void*>(mega),
                             dim3(NB), dim3(NT), args, 0, stream);
}